// Round 1
// baseline (911.280 us; speedup 1.0000x reference)
//
#include <hip/hip_runtime.h>

#define D 256
#define SLOPE 0.01f

typedef __attribute__((ext_vector_type(8))) short bf16x8;
typedef __attribute__((ext_vector_type(4))) float f32x4;

__device__ __forceinline__ float bfbits2f(unsigned int hi) {
  return __builtin_bit_cast(float, hi);
}
__device__ __forceinline__ unsigned short f2bf(float f) {
  unsigned u = __builtin_bit_cast(unsigned, f);
  u += 0x7fffu + ((u >> 16) & 1u);
  return (unsigned short)(u >> 16);
}

__device__ __forceinline__ void gld_lds16(const void* g, void* l) {
  __builtin_amdgcn_global_load_lds(
      (const __attribute__((address_space(1))) unsigned int*)g,
      (__attribute__((address_space(3))) unsigned int*)l, 16, 0, 0);
}

// ---------------- cast fp32 -> bf16 (vectorized x4) ----------------
__global__ void cast_kernel(const float* __restrict__ in,
                            unsigned short* __restrict__ out, int n4) {
  int i = blockIdx.x * blockDim.x + threadIdx.x;
  if (i >= n4) return;
  float4 v = ((const float4*)in)[i];
  ushort4 o;
  o.x = f2bf(v.x); o.y = f2bf(v.y); o.z = f2bf(v.z); o.w = f2bf(v.w);
  ((ushort4*)out)[i] = o;
}

// ---------------- bf16 MFMA GEMM: C = lrelu(A @ B^T + bias) [+ residual] ----
// A: [M,256] bf16 row-major. B: [256,256] bf16 row-major (rows = out cols).
// MODE 0: out bf16.  MODE 1: out fp32 with residual add.
template <int MODE>
__global__ __launch_bounds__(256) void gemm_bt(
    const unsigned short* __restrict__ A, const unsigned short* __restrict__ B,
    const float* __restrict__ bias, const float* __restrict__ residual,
    unsigned short* __restrict__ outb, float* __restrict__ outf, int M) {
  __shared__ __attribute__((aligned(16))) unsigned short As[128 * 32];
  __shared__ __attribute__((aligned(16))) unsigned short Bs[128 * 32];
  int t = threadIdx.x;
  int w = t >> 6, lane = t & 63;
  int mblk = blockIdx.y * 128, nblk = blockIdx.x * 128;
  int wm = (w >> 1) * 64, wn = (w & 1) * 64;

  f32x4 acc[4][4];
#pragma unroll
  for (int i = 0; i < 4; i++)
#pragma unroll
    for (int j = 0; j < 4; j++) acc[i][j] = (f32x4){0.f, 0.f, 0.f, 0.f};

  int lrow = lane >> 2;          // 0..15
  int lcol = (lane & 3) * 8;     // 0,8,16,24
  int ar0 = mblk + w * 16 + lrow;       if (ar0 > M - 1) ar0 = M - 1;
  int ar1 = mblk + 64 + w * 16 + lrow;  if (ar1 > M - 1) ar1 = M - 1;
  int br0 = nblk + w * 16 + lrow;
  int br1 = nblk + 64 + w * 16 + lrow;
  const unsigned short* a0 = A + (size_t)ar0 * D + lcol;
  const unsigned short* a1 = A + (size_t)ar1 * D + lcol;
  const unsigned short* b0 = B + (size_t)br0 * D + lcol;
  const unsigned short* b1 = B + (size_t)br1 * D + lcol;
  unsigned short* lA0 = &As[(w * 16) * 32];
  unsigned short* lA1 = &As[(64 + w * 16) * 32];
  unsigned short* lB0 = &Bs[(w * 16) * 32];
  unsigned short* lB1 = &Bs[(64 + w * 16) * 32];

  int fr = lane & 15;
  int fk = (lane >> 4) * 8;

  for (int k0 = 0; k0 < D; k0 += 32) {
    gld_lds16(a0 + k0, lA0);
    gld_lds16(a1 + k0, lA1);
    gld_lds16(b0 + k0, lB0);
    gld_lds16(b1 + k0, lB1);
    asm volatile("s_waitcnt vmcnt(0)" ::: "memory");
    __syncthreads();
    bf16x8 af[4], bfr[4];
#pragma unroll
    for (int mt = 0; mt < 4; mt++)
      af[mt] = *(const bf16x8*)&As[(wm + mt * 16 + fr) * 32 + fk];
#pragma unroll
    for (int nt = 0; nt < 4; nt++)
      bfr[nt] = *(const bf16x8*)&Bs[(wn + nt * 16 + fr) * 32 + fk];
#pragma unroll
    for (int mt = 0; mt < 4; mt++)
#pragma unroll
      for (int nt = 0; nt < 4; nt++)
        acc[mt][nt] = __builtin_amdgcn_mfma_f32_16x16x32_bf16(
            af[mt], bfr[nt], acc[mt][nt], 0, 0, 0);
    __syncthreads();
  }

  // epilogue: C/D layout col=lane&15, row=(lane>>4)*4+r
#pragma unroll
  for (int nt = 0; nt < 4; nt++) {
    int col = nblk + wn + nt * 16 + (lane & 15);
    float bv = bias[col];
#pragma unroll
    for (int mt = 0; mt < 4; mt++) {
      int row = mblk + wm + mt * 16 + (lane >> 4) * 4;
#pragma unroll
      for (int r = 0; r < 4; r++) {
        int rr = row + r;
        if (rr < M) {
          float x = acc[mt][nt][r] + bv;
          x = (x >= 0.f) ? x : SLOPE * x;
          size_t idx = (size_t)rr * D + col;
          if (MODE == 0) {
            outb[idx] = f2bf(x);
          } else {
            outf[idx] = x + residual[idx];
          }
        }
      }
    }
  }
}

// ---------------- CSR build ----------------
__global__ void hist_kernel(const int* __restrict__ dst, int n,
                            int* __restrict__ cnt) {
  int i = blockIdx.x * blockDim.x + threadIdx.x;
  if (i < n) atomicAdd(&cnt[dst[i]], 1);
}

__global__ __launch_bounds__(1024) void scan4_kernel(
    const int* c0, int* o0, int n0, const int* c1, int* o1, int n1,
    const int* c2, int* o2, int n2, const int* c3, int* o3, int n3) {
  __shared__ int sums[1024];
  const int* cnt; int* offs; int n;
  if (blockIdx.x == 0) { cnt = c0; offs = o0; n = n0; }
  else if (blockIdx.x == 1) { cnt = c1; offs = o1; n = n1; }
  else if (blockIdx.x == 2) { cnt = c2; offs = o2; n = n2; }
  else { cnt = c3; offs = o3; n = n3; }
  int t = threadIdx.x;
  int per = (n + 1023) >> 10;
  int b = t * per, e = b + per;
  if (b > n) b = n;
  if (e > n) e = n;
  int s = 0;
  for (int i = b; i < e; i++) s += cnt[i];
  sums[t] = s;
  __syncthreads();
  for (int off = 1; off < 1024; off <<= 1) {
    int u = (t >= off) ? sums[t - off] : 0;
    __syncthreads();
    sums[t] += u;
    __syncthreads();
  }
  int run = sums[t] - s;
  for (int i = b; i < e; i++) { offs[i] = run; run += cnt[i]; }
  if (t == 1023) offs[n] = sums[1023];
}

__global__ void scatter_kernel(const int* __restrict__ src,
                               const int* __restrict__ dst, int n,
                               const int* __restrict__ offs,
                               int* __restrict__ cur, int* __restrict__ elist) {
  int i = blockIdx.x * blockDim.x + threadIdx.x;
  if (i < n) {
    int d = dst[i];
    int p = offs[d] + atomicAdd(&cur[d], 1);
    elist[p] = src[i];
  }
}

// ---------------- aggregation: one wave per dst node, two etypes fused ------
__global__ __launch_bounds__(256) void aggregate_kernel(
    const unsigned short* __restrict__ WhA, const int* __restrict__ offsA,
    const int* __restrict__ elistA, const unsigned short* __restrict__ WhB,
    const int* __restrict__ offsB, const int* __restrict__ elistB,
    unsigned short* __restrict__ hout, int n) {
  int wave = (blockIdx.x * 256 + threadIdx.x) >> 6;
  int lane = threadIdx.x & 63;
  if (wave >= n) return;

  float h0 = 0.f, h1 = 0.f, h2 = 0.f, h3 = 0.f;
  {
    float a0 = 0.f, a1 = 0.f, a2 = 0.f, a3 = 0.f;
    int e0 = offsA[wave], e1 = offsA[wave + 1];
    for (int e = e0; e < e1; e++) {
      int s = elistA[e];
      uint2 p = *(const uint2*)(WhA + (size_t)s * D + lane * 4);
      a0 += bfbits2f(p.x << 16);
      a1 += bfbits2f(p.x & 0xffff0000u);
      a2 += bfbits2f(p.y << 16);
      a3 += bfbits2f(p.y & 0xffff0000u);
    }
    float sc = 0.5f / fmaxf((float)(e1 - e0), 1.0f);
    h0 += a0 * sc; h1 += a1 * sc; h2 += a2 * sc; h3 += a3 * sc;
  }
  {
    float a0 = 0.f, a1 = 0.f, a2 = 0.f, a3 = 0.f;
    int e0 = offsB[wave], e1 = offsB[wave + 1];
    for (int e = e0; e < e1; e++) {
      int s = elistB[e];
      uint2 p = *(const uint2*)(WhB + (size_t)s * D + lane * 4);
      a0 += bfbits2f(p.x << 16);
      a1 += bfbits2f(p.x & 0xffff0000u);
      a2 += bfbits2f(p.y << 16);
      a3 += bfbits2f(p.y & 0xffff0000u);
    }
    float sc = 0.5f / fmaxf((float)(e1 - e0), 1.0f);
    h0 += a0 * sc; h1 += a1 * sc; h2 += a2 * sc; h3 += a3 * sc;
  }
  uint2 o;
  o.x = (unsigned)f2bf(h0) | ((unsigned)f2bf(h1) << 16);
  o.y = (unsigned)f2bf(h2) | ((unsigned)f2bf(h3) << 16);
  *(uint2*)(hout + (size_t)wave * D + lane * 4) = o;
}

// ---------------- launch ----------------
extern "C" void kernel_launch(void* const* d_in, const int* in_sizes, int n_in,
                              void* d_out, int out_size, void* d_ws,
                              size_t ws_size, hipStream_t stream) {
  const float* feat_table = (const float*)d_in[0];
  const float* feat_column = (const float*)d_in[1];
  const float* Wsrc[5] = {(const float*)d_in[2], (const float*)d_in[4],
                          (const float*)d_in[6], (const float*)d_in[8],
                          (const float*)d_in[10]};
  const float* b_t2c = (const float*)d_in[3];
  const float* b_c2t = (const float*)d_in[5];
  const float* b_c2c = (const float*)d_in[7];
  const float* b_t2t = (const float*)d_in[9];
  const float* b_h = (const float*)d_in[11];
  const int* src_t2c = (const int*)d_in[12];
  const int* dst_t2c = (const int*)d_in[13];
  const int* src_c2t = (const int*)d_in[14];
  const int* dst_c2t = (const int*)d_in[15];
  const int* src_c2c = (const int*)d_in[16];
  const int* dst_c2c = (const int*)d_in[17];
  const int* src_t2t = (const int*)d_in[18];
  const int* dst_t2t = (const int*)d_in[19];

  const int NT = in_sizes[0] / D;
  const int NC = in_sizes[1] / D;
  const int E_t2c = in_sizes[12], E_c2t = in_sizes[14];
  const int E_c2c = in_sizes[16], E_t2t = in_sizes[18];

  char* ws = (char*)d_ws;
  size_t cur = 0;
  auto alloc = [&](size_t bytes) -> void* {
    void* p = ws + cur;
    cur += (bytes + 255) & ~(size_t)255;
    return p;
  };
  unsigned short* Wb[5];
  for (int i = 0; i < 5; i++) Wb[i] = (unsigned short*)alloc((size_t)D * D * 2);
  unsigned short* ftb = (unsigned short*)alloc((size_t)NT * D * 2);
  unsigned short* fcb = (unsigned short*)alloc((size_t)NC * D * 2);
  unsigned short* Wh_t2c = (unsigned short*)alloc((size_t)NT * D * 2);
  unsigned short* Wh_c2t = (unsigned short*)alloc((size_t)NC * D * 2);
  unsigned short* Wh_c2c = (unsigned short*)alloc((size_t)NC * D * 2);
  unsigned short* Wh_t2t = (unsigned short*)alloc((size_t)NT * D * 2);
  unsigned short* h_tab = (unsigned short*)alloc((size_t)NT * D * 2);
  unsigned short* h_col = (unsigned short*)alloc((size_t)NC * D * 2);
  int* ints = (int*)alloc(sizeof(int) * 2 * (2 * (size_t)NT + 2 * (size_t)NC));
  int* cnt_c2t = ints;
  int* cnt_t2t = cnt_c2t + NT;
  int* cnt_t2c = cnt_t2t + NT;
  int* cnt_c2c = cnt_t2c + NC;
  int* cur_c2t = cnt_c2c + NC;
  int* cur_t2t = cur_c2t + NT;
  int* cur_t2c = cur_t2t + NT;
  int* cur_c2c = cur_t2c + NC;
  int* off_c2t = (int*)alloc(sizeof(int) * (NT + 1));
  int* off_t2t = (int*)alloc(sizeof(int) * (NT + 1));
  int* off_t2c = (int*)alloc(sizeof(int) * (NC + 1));
  int* off_c2c = (int*)alloc(sizeof(int) * (NC + 1));
  int* el_c2t = (int*)alloc(sizeof(int) * E_c2t);
  int* el_t2t = (int*)alloc(sizeof(int) * E_t2t);
  int* el_t2c = (int*)alloc(sizeof(int) * E_t2c);
  int* el_c2c = (int*)alloc(sizeof(int) * E_c2c);

  hipMemsetAsync(ints, 0, sizeof(int) * 2 * (2 * (size_t)NT + 2 * (size_t)NC),
                 stream);

  auto cast = [&](const float* in, unsigned short* out, size_t n) {
    int n4 = (int)(n / 4);
    cast_kernel<<<(n4 + 255) / 256, 256, 0, stream>>>(in, out, n4);
  };
  for (int i = 0; i < 5; i++) cast(Wsrc[i], Wb[i], (size_t)D * D);
  cast(feat_table, ftb, (size_t)NT * D);
  cast(feat_column, fcb, (size_t)NC * D);

  // Wh = lrelu(feat @ W^T + b), bf16 out
  {
    dim3 g(2, (NT + 127) / 128);
    gemm_bt<0><<<g, 256, 0, stream>>>(ftb, Wb[0], b_t2c, nullptr, Wh_t2c,
                                      nullptr, NT);
  }
  {
    dim3 g(2, (NC + 127) / 128);
    gemm_bt<0><<<g, 256, 0, stream>>>(fcb, Wb[1], b_c2t, nullptr, Wh_c2t,
                                      nullptr, NC);
  }
  {
    dim3 g(2, (NC + 127) / 128);
    gemm_bt<0><<<g, 256, 0, stream>>>(fcb, Wb[2], b_c2c, nullptr, Wh_c2c,
                                      nullptr, NC);
  }
  {
    dim3 g(2, (NT + 127) / 128);
    gemm_bt<0><<<g, 256, 0, stream>>>(ftb, Wb[3], b_t2t, nullptr, Wh_t2t,
                                      nullptr, NT);
  }

  // CSR build
  hist_kernel<<<(E_c2t + 255) / 256, 256, 0, stream>>>(dst_c2t, E_c2t, cnt_c2t);
  hist_kernel<<<(E_t2t + 255) / 256, 256, 0, stream>>>(dst_t2t, E_t2t, cnt_t2t);
  hist_kernel<<<(E_t2c + 255) / 256, 256, 0, stream>>>(dst_t2c, E_t2c, cnt_t2c);
  hist_kernel<<<(E_c2c + 255) / 256, 256, 0, stream>>>(dst_c2c, E_c2c, cnt_c2c);
  scan4_kernel<<<4, 1024, 0, stream>>>(cnt_c2t, off_c2t, NT, cnt_t2t, off_t2t,
                                       NT, cnt_t2c, off_t2c, NC, cnt_c2c,
                                       off_c2c, NC);
  scatter_kernel<<<(E_c2t + 255) / 256, 256, 0, stream>>>(
      src_c2t, dst_c2t, E_c2t, off_c2t, cur_c2t, el_c2t);
  scatter_kernel<<<(E_t2t + 255) / 256, 256, 0, stream>>>(
      src_t2t, dst_t2t, E_t2t, off_t2t, cur_t2t, el_t2t);
  scatter_kernel<<<(E_t2c + 255) / 256, 256, 0, stream>>>(
      src_t2c, dst_t2c, E_t2c, off_t2c, cur_t2c, el_t2c);
  scatter_kernel<<<(E_c2c + 255) / 256, 256, 0, stream>>>(
      src_c2c, dst_c2c, E_c2c, off_c2c, cur_c2c, el_c2c);

  // h = 0.5*(meanA + meanB), bf16 out
  aggregate_kernel<<<(NT + 3) / 4, 256, 0, stream>>>(
      Wh_c2t, off_c2t, el_c2t, Wh_t2t, off_t2t, el_t2t, h_tab, NT);
  aggregate_kernel<<<(NC + 3) / 4, 256, 0, stream>>>(
      Wh_t2c, off_t2c, el_t2c, Wh_c2c, off_c2c, el_c2c, h_col, NC);

  // out = lrelu(h @ W_h^T + b_h) + feat, fp32 out
  float* out_tab = (float*)d_out;
  float* out_col = out_tab + (size_t)NT * D;
  {
    dim3 g(2, (NT + 127) / 128);
    gemm_bt<1><<<g, 256, 0, stream>>>(h_tab, Wb[4], b_h, feat_table, nullptr,
                                      out_tab, NT);
  }
  {
    dim3 g(2, (NC + 127) / 128);
    gemm_bt<1><<<g, 256, 0, stream>>>(h_col, Wb[4], b_h, feat_column, nullptr,
                                      out_col, NC);
  }
}

// Round 2
// 775.805 us; speedup vs baseline: 1.1746x; 1.1746x over previous
//
#include <hip/hip_runtime.h>

#define D 256
#define SLOPE 0.01f

typedef __attribute__((ext_vector_type(8))) short bf16x8;
typedef __attribute__((ext_vector_type(4))) float f32x4;

__device__ __forceinline__ float bfbits2f(unsigned int hi) {
  return __builtin_bit_cast(float, hi);
}
__device__ __forceinline__ unsigned short f2bf(float f) {
  unsigned u = __builtin_bit_cast(unsigned, f);
  u += 0x7fffu + ((u >> 16) & 1u);
  return (unsigned short)(u >> 16);
}

__device__ __forceinline__ void gld_lds16(const void* g, void* l) {
  __builtin_amdgcn_global_load_lds(
      (const __attribute__((address_space(1))) unsigned int*)g,
      (__attribute__((address_space(3))) unsigned int*)l, 16, 0, 0);
}

// ---------------- cast fp32 -> bf16 (vectorized x4) ----------------
__global__ void cast_kernel(const float* __restrict__ in,
                            unsigned short* __restrict__ out, int n4) {
  int i = blockIdx.x * blockDim.x + threadIdx.x;
  if (i >= n4) return;
  float4 v = ((const float4*)in)[i];
  ushort4 o;
  o.x = f2bf(v.x); o.y = f2bf(v.y); o.z = f2bf(v.z); o.w = f2bf(v.w);
  ((ushort4*)out)[i] = o;
}

// batched weight cast: 5 weights of D*D floats each
__global__ void cast5_kernel(const float* w0, const float* w1, const float* w2,
                             const float* w3, const float* w4,
                             unsigned short* o0, unsigned short* o1,
                             unsigned short* o2, unsigned short* o3,
                             unsigned short* o4) {
  int a = blockIdx.y;
  const float* in = a == 0 ? w0 : a == 1 ? w1 : a == 2 ? w2 : a == 3 ? w3 : w4;
  unsigned short* out = a == 0 ? o0 : a == 1 ? o1 : a == 2 ? o2 : a == 3 ? o3 : o4;
  int i = blockIdx.x * blockDim.x + threadIdx.x;  // over D*D/4
  float4 v = ((const float4*)in)[i];
  ushort4 o;
  o.x = f2bf(v.x); o.y = f2bf(v.y); o.z = f2bf(v.z); o.w = f2bf(v.w);
  ((ushort4*)out)[i] = o;
}

// ---------------- bf16 MFMA GEMM: C = lrelu(A @ B^T + bias) [+ residual] ----
template <int MODE>
__global__ __launch_bounds__(256) void gemm_bt(
    const unsigned short* __restrict__ A, const unsigned short* __restrict__ B,
    const float* __restrict__ bias, const float* __restrict__ residual,
    unsigned short* __restrict__ outb, float* __restrict__ outf, int M) {
  __shared__ __attribute__((aligned(16))) unsigned short As[128 * 32];
  __shared__ __attribute__((aligned(16))) unsigned short Bs[128 * 32];
  int t = threadIdx.x;
  int w = t >> 6, lane = t & 63;
  int mblk = blockIdx.y * 128, nblk = blockIdx.x * 128;
  int wm = (w >> 1) * 64, wn = (w & 1) * 64;

  f32x4 acc[4][4];
#pragma unroll
  for (int i = 0; i < 4; i++)
#pragma unroll
    for (int j = 0; j < 4; j++) acc[i][j] = (f32x4){0.f, 0.f, 0.f, 0.f};

  int lrow = lane >> 2;          // 0..15
  int lcol = (lane & 3) * 8;     // 0,8,16,24
  int ar0 = mblk + w * 16 + lrow;       if (ar0 > M - 1) ar0 = M - 1;
  int ar1 = mblk + 64 + w * 16 + lrow;  if (ar1 > M - 1) ar1 = M - 1;
  int br0 = nblk + w * 16 + lrow;
  int br1 = nblk + 64 + w * 16 + lrow;
  const unsigned short* a0 = A + (size_t)ar0 * D + lcol;
  const unsigned short* a1 = A + (size_t)ar1 * D + lcol;
  const unsigned short* b0 = B + (size_t)br0 * D + lcol;
  const unsigned short* b1 = B + (size_t)br1 * D + lcol;
  unsigned short* lA0 = &As[(w * 16) * 32];
  unsigned short* lA1 = &As[(64 + w * 16) * 32];
  unsigned short* lB0 = &Bs[(w * 16) * 32];
  unsigned short* lB1 = &Bs[(64 + w * 16) * 32];

  int fr = lane & 15;
  int fk = (lane >> 4) * 8;

  for (int k0 = 0; k0 < D; k0 += 32) {
    gld_lds16(a0 + k0, lA0);
    gld_lds16(a1 + k0, lA1);
    gld_lds16(b0 + k0, lB0);
    gld_lds16(b1 + k0, lB1);
    asm volatile("s_waitcnt vmcnt(0)" ::: "memory");
    __syncthreads();
    bf16x8 af[4], bfr[4];
#pragma unroll
    for (int mt = 0; mt < 4; mt++)
      af[mt] = *(const bf16x8*)&As[(wm + mt * 16 + fr) * 32 + fk];
#pragma unroll
    for (int nt = 0; nt < 4; nt++)
      bfr[nt] = *(const bf16x8*)&Bs[(wn + nt * 16 + fr) * 32 + fk];
#pragma unroll
    for (int mt = 0; mt < 4; mt++)
#pragma unroll
      for (int nt = 0; nt < 4; nt++)
        acc[mt][nt] = __builtin_amdgcn_mfma_f32_16x16x32_bf16(
            af[mt], bfr[nt], acc[mt][nt], 0, 0, 0);
    __syncthreads();
  }

#pragma unroll
  for (int nt = 0; nt < 4; nt++) {
    int col = nblk + wn + nt * 16 + (lane & 15);
    float bv = bias[col];
#pragma unroll
    for (int mt = 0; mt < 4; mt++) {
      int row = mblk + wm + mt * 16 + (lane >> 4) * 4;
#pragma unroll
      for (int r = 0; r < 4; r++) {
        int rr = row + r;
        if (rr < M) {
          float x = acc[mt][nt][r] + bv;
          x = (x >= 0.f) ? x : SLOPE * x;
          size_t idx = (size_t)rr * D + col;
          if (MODE == 0) {
            outb[idx] = f2bf(x);
          } else {
            outf[idx] = x + residual[idx];
          }
        }
      }
    }
  }
}

// ---------------- CSR build ----------------
__global__ void hist4_kernel(const int* d0, int n0, int* c0, const int* d1,
                             int n1, int* c1, const int* d2, int n2, int* c2,
                             const int* d3, int n3, int* c3) {
  int a = blockIdx.y;
  const int* dst = a == 0 ? d0 : a == 1 ? d1 : a == 2 ? d2 : d3;
  int n = a == 0 ? n0 : a == 1 ? n1 : a == 2 ? n2 : n3;
  int* cnt = a == 0 ? c0 : a == 1 ? c1 : a == 2 ? c2 : c3;
  int i = blockIdx.x * blockDim.x + threadIdx.x;
  if (i < n) atomicAdd(&cnt[dst[i]], 1);
}

// 3-phase batched exclusive scan over 4 arrays (chunk = 1024 ints/block)
__global__ __launch_bounds__(256) void scan_p1(
    const int* c0, int n0, const int* c1, int n1, const int* c2, int n2,
    const int* c3, int n3, int* __restrict__ bsum) {
  int a = blockIdx.y;
  const int* cnt = a == 0 ? c0 : a == 1 ? c1 : a == 2 ? c2 : c3;
  int n = a == 0 ? n0 : a == 1 ? n1 : a == 2 ? n2 : n3;
  int nblk = (n + 1023) >> 10;
  int blk = blockIdx.x;
  if (blk >= nblk) return;
  int t = threadIdx.x;
  int i = (blk << 10) + t * 4;
  int s = 0;
  if (i + 3 < n) {
    int4 v = *(const int4*)(cnt + i);
    s = v.x + v.y + v.z + v.w;
  } else {
#pragma unroll
    for (int j = 0; j < 4; j++)
      if (i + j < n) s += cnt[i + j];
  }
  __shared__ int red[256];
  red[t] = s;
  __syncthreads();
  for (int off = 128; off > 0; off >>= 1) {
    if (t < off) red[t] += red[t + off];
    __syncthreads();
  }
  if (t == 0) bsum[a * 128 + blk] = red[0];
}

__global__ __launch_bounds__(128) void scan_p2(int* __restrict__ bsum, int* o0,
                                               int n0, int* o1, int n1, int* o2,
                                               int n2, int* o3, int n3) {
  int a = blockIdx.x;
  int* offs = a == 0 ? o0 : a == 1 ? o1 : a == 2 ? o2 : o3;
  int n = a == 0 ? n0 : a == 1 ? n1 : a == 2 ? n2 : n3;
  int nblk = (n + 1023) >> 10;
  int t = threadIdx.x;
  int v = (t < nblk) ? bsum[a * 128 + t] : 0;
  __shared__ int s[128];
  s[t] = v;
  __syncthreads();
  for (int off = 1; off < 128; off <<= 1) {
    int u = (t >= off) ? s[t - off] : 0;
    __syncthreads();
    s[t] += u;
    __syncthreads();
  }
  if (t < nblk) bsum[a * 128 + t] = s[t] - v;  // exclusive
  if (t == 127) offs[n] = s[127];              // grand total
}

__global__ __launch_bounds__(256) void scan_p3(
    const int* c0, int* o0, int n0, const int* c1, int* o1, int n1,
    const int* c2, int* o2, int n2, const int* c3, int* o3, int n3,
    const int* __restrict__ bsum) {
  int a = blockIdx.y;
  const int* cnt = a == 0 ? c0 : a == 1 ? c1 : a == 2 ? c2 : c3;
  int* offs = a == 0 ? o0 : a == 1 ? o1 : a == 2 ? o2 : o3;
  int n = a == 0 ? n0 : a == 1 ? n1 : a == 2 ? n2 : n3;
  int nblk = (n + 1023) >> 10;
  int blk = blockIdx.x;
  if (blk >= nblk) return;
  int t = threadIdx.x;
  int i = (blk << 10) + t * 4;
  int4 v = {0, 0, 0, 0};
  if (i + 3 < n) {
    v = *(const int4*)(cnt + i);
  } else {
    if (i < n) v.x = cnt[i];
    if (i + 1 < n) v.y = cnt[i + 1];
    if (i + 2 < n) v.z = cnt[i + 2];
    if (i + 3 < n) v.w = cnt[i + 3];
  }
  int s = v.x + v.y + v.z + v.w;
  __shared__ int sm[256];
  sm[t] = s;
  __syncthreads();
  for (int off = 1; off < 256; off <<= 1) {
    int u = (t >= off) ? sm[t - off] : 0;
    __syncthreads();
    sm[t] += u;
    __syncthreads();
  }
  int ex = sm[t] - s + bsum[a * 128 + blk];
  int4 o;
  o.x = ex;
  o.y = ex + v.x;
  o.z = ex + v.x + v.y;
  o.w = ex + v.x + v.y + v.z;
  if (i + 3 < n) {
    *(int4*)(offs + i) = o;
  } else {
    if (i < n) offs[i] = o.x;
    if (i + 1 < n) offs[i + 1] = o.y;
    if (i + 2 < n) offs[i + 2] = o.z;
    if (i + 3 < n) offs[i + 3] = o.w;
  }
}

__global__ void scatter4_kernel(
    const int* s0, const int* d0, int n0, const int* f0, int* u0, int* e0,
    const int* s1, const int* d1, int n1, const int* f1, int* u1, int* e1,
    const int* s2, const int* d2, int n2, const int* f2, int* u2, int* e2,
    const int* s3, const int* d3, int n3, const int* f3, int* u3, int* e3) {
  int a = blockIdx.y;
  const int* src = a == 0 ? s0 : a == 1 ? s1 : a == 2 ? s2 : s3;
  const int* dst = a == 0 ? d0 : a == 1 ? d1 : a == 2 ? d2 : d3;
  int n = a == 0 ? n0 : a == 1 ? n1 : a == 2 ? n2 : n3;
  const int* offs = a == 0 ? f0 : a == 1 ? f1 : a == 2 ? f2 : f3;
  int* cur = a == 0 ? u0 : a == 1 ? u1 : a == 2 ? u2 : u3;
  int* elist = a == 0 ? e0 : a == 1 ? e1 : a == 2 ? e2 : e3;
  int i = blockIdx.x * blockDim.x + threadIdx.x;
  if (i < n) {
    int d = dst[i];
    int p = offs[d] + atomicAdd(&cur[d], 1);
    elist[p] = src[i];
  }
}

// ---------------- aggregation: one wave per dst node, two etypes fused ------
__global__ __launch_bounds__(256) void aggregate_kernel(
    const unsigned short* __restrict__ WhA, const int* __restrict__ offsA,
    const int* __restrict__ elistA, const unsigned short* __restrict__ WhB,
    const int* __restrict__ offsB, const int* __restrict__ elistB,
    unsigned short* __restrict__ hout, int n) {
  int wave = (blockIdx.x * 256 + threadIdx.x) >> 6;
  int lane = threadIdx.x & 63;
  if (wave >= n) return;

  float h0 = 0.f, h1 = 0.f, h2 = 0.f, h3 = 0.f;
  {
    float a0 = 0.f, a1 = 0.f, a2 = 0.f, a3 = 0.f;
    int e0 = offsA[wave], e1 = offsA[wave + 1];
    for (int e = e0; e < e1; e++) {
      int s = elistA[e];
      uint2 p = *(const uint2*)(WhA + (size_t)s * D + lane * 4);
      a0 += bfbits2f(p.x << 16);
      a1 += bfbits2f(p.x & 0xffff0000u);
      a2 += bfbits2f(p.y << 16);
      a3 += bfbits2f(p.y & 0xffff0000u);
    }
    float sc = 0.5f / fmaxf((float)(e1 - e0), 1.0f);
    h0 += a0 * sc; h1 += a1 * sc; h2 += a2 * sc; h3 += a3 * sc;
  }
  {
    float a0 = 0.f, a1 = 0.f, a2 = 0.f, a3 = 0.f;
    int e0 = offsB[wave], e1 = offsB[wave + 1];
    for (int e = e0; e < e1; e++) {
      int s = elistB[e];
      uint2 p = *(const uint2*)(WhB + (size_t)s * D + lane * 4);
      a0 += bfbits2f(p.x << 16);
      a1 += bfbits2f(p.x & 0xffff0000u);
      a2 += bfbits2f(p.y << 16);
      a3 += bfbits2f(p.y & 0xffff0000u);
    }
    float sc = 0.5f / fmaxf((float)(e1 - e0), 1.0f);
    h0 += a0 * sc; h1 += a1 * sc; h2 += a2 * sc; h3 += a3 * sc;
  }
  uint2 o;
  o.x = (unsigned)f2bf(h0) | ((unsigned)f2bf(h1) << 16);
  o.y = (unsigned)f2bf(h2) | ((unsigned)f2bf(h3) << 16);
  *(uint2*)(hout + (size_t)wave * D + lane * 4) = o;
}

// ---------------- launch ----------------
extern "C" void kernel_launch(void* const* d_in, const int* in_sizes, int n_in,
                              void* d_out, int out_size, void* d_ws,
                              size_t ws_size, hipStream_t stream) {
  const float* feat_table = (const float*)d_in[0];
  const float* feat_column = (const float*)d_in[1];
  const float* Wsrc[5] = {(const float*)d_in[2], (const float*)d_in[4],
                          (const float*)d_in[6], (const float*)d_in[8],
                          (const float*)d_in[10]};
  const float* b_t2c = (const float*)d_in[3];
  const float* b_c2t = (const float*)d_in[5];
  const float* b_c2c = (const float*)d_in[7];
  const float* b_t2t = (const float*)d_in[9];
  const float* b_h = (const float*)d_in[11];
  const int* src_t2c = (const int*)d_in[12];
  const int* dst_t2c = (const int*)d_in[13];
  const int* src_c2t = (const int*)d_in[14];
  const int* dst_c2t = (const int*)d_in[15];
  const int* src_c2c = (const int*)d_in[16];
  const int* dst_c2c = (const int*)d_in[17];
  const int* src_t2t = (const int*)d_in[18];
  const int* dst_t2t = (const int*)d_in[19];

  const int NT = in_sizes[0] / D;
  const int NC = in_sizes[1] / D;
  const int E_t2c = in_sizes[12], E_c2t = in_sizes[14];
  const int E_c2c = in_sizes[16], E_t2t = in_sizes[18];

  char* ws = (char*)d_ws;
  size_t cur = 0;
  auto alloc = [&](size_t bytes) -> void* {
    void* p = ws + cur;
    cur += (bytes + 255) & ~(size_t)255;
    return p;
  };
  unsigned short* Wb[5];
  for (int i = 0; i < 5; i++) Wb[i] = (unsigned short*)alloc((size_t)D * D * 2);
  unsigned short* ftb = (unsigned short*)alloc((size_t)NT * D * 2);
  unsigned short* fcb = (unsigned short*)alloc((size_t)NC * D * 2);
  unsigned short* Wh_t2c = (unsigned short*)alloc((size_t)NT * D * 2);
  unsigned short* Wh_c2t = (unsigned short*)alloc((size_t)NC * D * 2);
  unsigned short* Wh_c2c = (unsigned short*)alloc((size_t)NC * D * 2);
  unsigned short* Wh_t2t = (unsigned short*)alloc((size_t)NT * D * 2);
  unsigned short* h_tab = (unsigned short*)alloc((size_t)NT * D * 2);
  unsigned short* h_col = (unsigned short*)alloc((size_t)NC * D * 2);
  int* ints = (int*)alloc(sizeof(int) * 2 * (2 * (size_t)NT + 2 * (size_t)NC));
  int* cnt_c2t = ints;
  int* cnt_t2t = cnt_c2t + NT;
  int* cnt_t2c = cnt_t2t + NT;
  int* cnt_c2c = cnt_t2c + NC;
  int* cur_c2t = cnt_c2c + NC;
  int* cur_t2t = cur_c2t + NT;
  int* cur_t2c = cur_t2t + NT;
  int* cur_c2c = cur_t2c + NC;
  int* off_c2t = (int*)alloc(sizeof(int) * (NT + 1));
  int* off_t2t = (int*)alloc(sizeof(int) * (NT + 1));
  int* off_t2c = (int*)alloc(sizeof(int) * (NC + 1));
  int* off_c2c = (int*)alloc(sizeof(int) * (NC + 1));
  int* el_c2t = (int*)alloc(sizeof(int) * E_c2t);
  int* el_t2t = (int*)alloc(sizeof(int) * E_t2t);
  int* el_t2c = (int*)alloc(sizeof(int) * E_t2c);
  int* el_c2c = (int*)alloc(sizeof(int) * E_c2c);
  int* bsum = (int*)alloc(sizeof(int) * 4 * 128);

  hipMemsetAsync(ints, 0, sizeof(int) * 2 * (2 * (size_t)NT + 2 * (size_t)NC),
                 stream);

  // casts
  {
    dim3 g((D * D / 4 + 255) / 256, 5);
    cast5_kernel<<<g, 256, 0, stream>>>(Wsrc[0], Wsrc[1], Wsrc[2], Wsrc[3],
                                        Wsrc[4], Wb[0], Wb[1], Wb[2], Wb[3],
                                        Wb[4]);
  }
  cast_kernel<<<((NT * D / 4) + 255) / 256, 256, 0, stream>>>(feat_table, ftb,
                                                              NT * D / 4);
  cast_kernel<<<((NC * D / 4) + 255) / 256, 256, 0, stream>>>(feat_column, fcb,
                                                              NC * D / 4);

  // Wh = lrelu(feat @ W^T + b), bf16 out
  {
    dim3 g(2, (NT + 127) / 128);
    gemm_bt<0><<<g, 256, 0, stream>>>(ftb, Wb[0], b_t2c, nullptr, Wh_t2c,
                                      nullptr, NT);
    gemm_bt<0><<<g, 256, 0, stream>>>(ftb, Wb[3], b_t2t, nullptr, Wh_t2t,
                                      nullptr, NT);
  }
  {
    dim3 g(2, (NC + 127) / 128);
    gemm_bt<0><<<g, 256, 0, stream>>>(fcb, Wb[1], b_c2t, nullptr, Wh_c2t,
                                      nullptr, NC);
    gemm_bt<0><<<g, 256, 0, stream>>>(fcb, Wb[2], b_c2c, nullptr, Wh_c2c,
                                      nullptr, NC);
  }

  // CSR build: hist -> 3-phase scan -> scatter
  int Emax = max(max(E_c2t, E_t2t), max(E_t2c, E_c2c));
  {
    dim3 g((Emax + 255) / 256, 4);
    hist4_kernel<<<g, 256, 0, stream>>>(dst_c2t, E_c2t, cnt_c2t, dst_t2t,
                                        E_t2t, cnt_t2t, dst_t2c, E_t2c,
                                        cnt_t2c, dst_c2c, E_c2c, cnt_c2c);
  }
  int nmax = max(NT, NC);
  {
    dim3 g((nmax + 1023) / 1024, 4);
    scan_p1<<<g, 256, 0, stream>>>(cnt_c2t, NT, cnt_t2t, NT, cnt_t2c, NC,
                                   cnt_c2c, NC, bsum);
    scan_p2<<<4, 128, 0, stream>>>(bsum, off_c2t, NT, off_t2t, NT, off_t2c, NC,
                                   off_c2c, NC);
    scan_p3<<<g, 256, 0, stream>>>(cnt_c2t, off_c2t, NT, cnt_t2t, off_t2t, NT,
                                   cnt_t2c, off_t2c, NC, cnt_c2c, off_c2c, NC,
                                   bsum);
  }
  {
    dim3 g((Emax + 255) / 256, 4);
    scatter4_kernel<<<g, 256, 0, stream>>>(
        src_c2t, dst_c2t, E_c2t, off_c2t, cur_c2t, el_c2t, src_t2t, dst_t2t,
        E_t2t, off_t2t, cur_t2t, el_t2t, src_t2c, dst_t2c, E_t2c, off_t2c,
        cur_t2c, el_t2c, src_c2c, dst_c2c, E_c2c, off_c2c, cur_c2c, el_c2c);
  }

  // h = 0.5*(meanA + meanB), bf16 out
  aggregate_kernel<<<(NT + 3) / 4, 256, 0, stream>>>(
      Wh_c2t, off_c2t, el_c2t, Wh_t2t, off_t2t, el_t2t, h_tab, NT);
  aggregate_kernel<<<(NC + 3) / 4, 256, 0, stream>>>(
      Wh_t2c, off_t2c, el_t2c, Wh_c2c, off_c2c, el_c2c, h_col, NC);

  // out = lrelu(h @ W_h^T + b_h) + feat, fp32 out
  float* out_tab = (float*)d_out;
  float* out_col = out_tab + (size_t)NT * D;
  {
    dim3 g(2, (NT + 127) / 128);
    gemm_bt<1><<<g, 256, 0, stream>>>(h_tab, Wb[4], b_h, feat_table, nullptr,
                                      out_tab, NT);
  }
  {
    dim3 g(2, (NC + 127) / 128);
    gemm_bt<1><<<g, 256, 0, stream>>>(h_col, Wb[4], b_h, feat_column, nullptr,
                                      out_col, NC);
  }
}

// Round 3
// 715.239 us; speedup vs baseline: 1.2741x; 1.0847x over previous
//
#include <hip/hip_runtime.h>

#define D 256
#define SLOPE 0.01f

typedef __attribute__((ext_vector_type(8))) short bf16x8;
typedef __attribute__((ext_vector_type(4))) float f32x4;

__device__ __forceinline__ float bfbits2f(unsigned int hi) {
  return __builtin_bit_cast(float, hi);
}
__device__ __forceinline__ unsigned short f2bf(float f) {
  unsigned u = __builtin_bit_cast(unsigned, f);
  u += 0x7fffu + ((u >> 16) & 1u);
  return (unsigned short)(u >> 16);
}

__device__ __forceinline__ void gld_lds16(const void* g, void* l) {
  __builtin_amdgcn_global_load_lds(
      (const __attribute__((address_space(1))) unsigned int*)g,
      (__attribute__((address_space(3))) unsigned int*)l, 16, 0, 0);
}

// ---------------- cast fp32 -> bf16 (vectorized x4) ----------------
__global__ void cast_kernel(const float* __restrict__ in,
                            unsigned short* __restrict__ out, int n4) {
  int i = blockIdx.x * blockDim.x + threadIdx.x;
  if (i >= n4) return;
  float4 v = ((const float4*)in)[i];
  ushort4 o;
  o.x = f2bf(v.x); o.y = f2bf(v.y); o.z = f2bf(v.z); o.w = f2bf(v.w);
  ((ushort4*)out)[i] = o;
}

// batched weight cast: 5 weights of D*D floats each
__global__ void cast5_kernel(const float* w0, const float* w1, const float* w2,
                             const float* w3, const float* w4,
                             unsigned short* o0, unsigned short* o1,
                             unsigned short* o2, unsigned short* o3,
                             unsigned short* o4) {
  int a = blockIdx.y;
  const float* in = a == 0 ? w0 : a == 1 ? w1 : a == 2 ? w2 : a == 3 ? w3 : w4;
  unsigned short* out = a == 0 ? o0 : a == 1 ? o1 : a == 2 ? o2 : a == 3 ? o3 : o4;
  int i = blockIdx.x * blockDim.x + threadIdx.x;  // over D*D/4
  float4 v = ((const float4*)in)[i];
  ushort4 o;
  o.x = f2bf(v.x); o.y = f2bf(v.y); o.z = f2bf(v.z); o.w = f2bf(v.w);
  ((ushort4*)out)[i] = o;
}

// ---------------- bf16 MFMA GEMM: C = lrelu(A @ B^T + bias) [+ residual] ----
template <int MODE>
__global__ __launch_bounds__(256) void gemm_bt(
    const unsigned short* __restrict__ A, const unsigned short* __restrict__ B,
    const float* __restrict__ bias, const float* __restrict__ residual,
    unsigned short* __restrict__ outb, float* __restrict__ outf, int M) {
  __shared__ __attribute__((aligned(16))) unsigned short As[128 * 32];
  __shared__ __attribute__((aligned(16))) unsigned short Bs[128 * 32];
  int t = threadIdx.x;
  int w = t >> 6, lane = t & 63;
  int mblk = blockIdx.y * 128, nblk = blockIdx.x * 128;
  int wm = (w >> 1) * 64, wn = (w & 1) * 64;

  f32x4 acc[4][4];
#pragma unroll
  for (int i = 0; i < 4; i++)
#pragma unroll
    for (int j = 0; j < 4; j++) acc[i][j] = (f32x4){0.f, 0.f, 0.f, 0.f};

  int lrow = lane >> 2;          // 0..15
  int lcol = (lane & 3) * 8;     // 0,8,16,24
  int ar0 = mblk + w * 16 + lrow;       if (ar0 > M - 1) ar0 = M - 1;
  int ar1 = mblk + 64 + w * 16 + lrow;  if (ar1 > M - 1) ar1 = M - 1;
  int br0 = nblk + w * 16 + lrow;
  int br1 = nblk + 64 + w * 16 + lrow;
  const unsigned short* a0 = A + (size_t)ar0 * D + lcol;
  const unsigned short* a1 = A + (size_t)ar1 * D + lcol;
  const unsigned short* b0 = B + (size_t)br0 * D + lcol;
  const unsigned short* b1 = B + (size_t)br1 * D + lcol;
  unsigned short* lA0 = &As[(w * 16) * 32];
  unsigned short* lA1 = &As[(64 + w * 16) * 32];
  unsigned short* lB0 = &Bs[(w * 16) * 32];
  unsigned short* lB1 = &Bs[(64 + w * 16) * 32];

  int fr = lane & 15;
  int fk = (lane >> 4) * 8;

  for (int k0 = 0; k0 < D; k0 += 32) {
    gld_lds16(a0 + k0, lA0);
    gld_lds16(a1 + k0, lA1);
    gld_lds16(b0 + k0, lB0);
    gld_lds16(b1 + k0, lB1);
    asm volatile("s_waitcnt vmcnt(0)" ::: "memory");
    __syncthreads();
    bf16x8 af[4], bfr[4];
#pragma unroll
    for (int mt = 0; mt < 4; mt++)
      af[mt] = *(const bf16x8*)&As[(wm + mt * 16 + fr) * 32 + fk];
#pragma unroll
    for (int nt = 0; nt < 4; nt++)
      bfr[nt] = *(const bf16x8*)&Bs[(wn + nt * 16 + fr) * 32 + fk];
#pragma unroll
    for (int mt = 0; mt < 4; mt++)
#pragma unroll
      for (int nt = 0; nt < 4; nt++)
        acc[mt][nt] = __builtin_amdgcn_mfma_f32_16x16x32_bf16(
            af[mt], bfr[nt], acc[mt][nt], 0, 0, 0);
    __syncthreads();
  }

#pragma unroll
  for (int nt = 0; nt < 4; nt++) {
    int col = nblk + wn + nt * 16 + (lane & 15);
    float bv = bias[col];
#pragma unroll
    for (int mt = 0; mt < 4; mt++) {
      int row = mblk + wm + mt * 16 + (lane >> 4) * 4;
#pragma unroll
      for (int r = 0; r < 4; r++) {
        int rr = row + r;
        if (rr < M) {
          float x = acc[mt][nt][r] + bv;
          x = (x >= 0.f) ? x : SLOPE * x;
          size_t idx = (size_t)rr * D + col;
          if (MODE == 0) {
            outb[idx] = f2bf(x);
          } else {
            outf[idx] = x + residual[idx];
          }
        }
      }
    }
  }
}

// ---------------- CSR build ----------------
__global__ void hist4_kernel(const int* d0, int n0, int* c0, const int* d1,
                             int n1, int* c1, const int* d2, int n2, int* c2,
                             const int* d3, int n3, int* c3) {
  int a = blockIdx.y;
  const int* dst = a == 0 ? d0 : a == 1 ? d1 : a == 2 ? d2 : d3;
  int n = a == 0 ? n0 : a == 1 ? n1 : a == 2 ? n2 : n3;
  int* cnt = a == 0 ? c0 : a == 1 ? c1 : a == 2 ? c2 : c3;
  int i = blockIdx.x * blockDim.x + threadIdx.x;
  if (i < n) atomicAdd(&cnt[dst[i]], 1);
}

// 3-phase batched exclusive scan over 4 arrays (chunk = 1024 ints/block)
__global__ __launch_bounds__(256) void scan_p1(
    const int* c0, int n0, const int* c1, int n1, const int* c2, int n2,
    const int* c3, int n3, int* __restrict__ bsum) {
  int a = blockIdx.y;
  const int* cnt = a == 0 ? c0 : a == 1 ? c1 : a == 2 ? c2 : c3;
  int n = a == 0 ? n0 : a == 1 ? n1 : a == 2 ? n2 : n3;
  int nblk = (n + 1023) >> 10;
  int blk = blockIdx.x;
  if (blk >= nblk) return;
  int t = threadIdx.x;
  int i = (blk << 10) + t * 4;
  int s = 0;
  if (i + 3 < n) {
    int4 v = *(const int4*)(cnt + i);
    s = v.x + v.y + v.z + v.w;
  } else {
#pragma unroll
    for (int j = 0; j < 4; j++)
      if (i + j < n) s += cnt[i + j];
  }
  __shared__ int red[256];
  red[t] = s;
  __syncthreads();
  for (int off = 128; off > 0; off >>= 1) {
    if (t < off) red[t] += red[t + off];
    __syncthreads();
  }
  if (t == 0) bsum[a * 128 + blk] = red[0];
}

__global__ __launch_bounds__(128) void scan_p2(int* __restrict__ bsum, int* o0,
                                               int n0, int* o1, int n1, int* o2,
                                               int n2, int* o3, int n3) {
  int a = blockIdx.x;
  int* offs = a == 0 ? o0 : a == 1 ? o1 : a == 2 ? o2 : o3;
  int n = a == 0 ? n0 : a == 1 ? n1 : a == 2 ? n2 : n3;
  int nblk = (n + 1023) >> 10;
  int t = threadIdx.x;
  int v = (t < nblk) ? bsum[a * 128 + t] : 0;
  __shared__ int s[128];
  s[t] = v;
  __syncthreads();
  for (int off = 1; off < 128; off <<= 1) {
    int u = (t >= off) ? s[t - off] : 0;
    __syncthreads();
    s[t] += u;
    __syncthreads();
  }
  if (t < nblk) bsum[a * 128 + t] = s[t] - v;  // exclusive
  if (t == 127) offs[n] = s[127];              // grand total
}

__global__ __launch_bounds__(256) void scan_p3(
    const int* c0, int* o0, int n0, const int* c1, int* o1, int n1,
    const int* c2, int* o2, int n2, const int* c3, int* o3, int n3,
    const int* __restrict__ bsum) {
  int a = blockIdx.y;
  const int* cnt = a == 0 ? c0 : a == 1 ? c1 : a == 2 ? c2 : c3;
  int* offs = a == 0 ? o0 : a == 1 ? o1 : a == 2 ? o2 : o3;
  int n = a == 0 ? n0 : a == 1 ? n1 : a == 2 ? n2 : n3;
  int nblk = (n + 1023) >> 10;
  int blk = blockIdx.x;
  if (blk >= nblk) return;
  int t = threadIdx.x;
  int i = (blk << 10) + t * 4;
  int4 v = {0, 0, 0, 0};
  if (i + 3 < n) {
    v = *(const int4*)(cnt + i);
  } else {
    if (i < n) v.x = cnt[i];
    if (i + 1 < n) v.y = cnt[i + 1];
    if (i + 2 < n) v.z = cnt[i + 2];
    if (i + 3 < n) v.w = cnt[i + 3];
  }
  int s = v.x + v.y + v.z + v.w;
  __shared__ int sm[256];
  sm[t] = s;
  __syncthreads();
  for (int off = 1; off < 256; off <<= 1) {
    int u = (t >= off) ? sm[t - off] : 0;
    __syncthreads();
    sm[t] += u;
    __syncthreads();
  }
  int ex = sm[t] - s + bsum[a * 128 + blk];
  int4 o;
  o.x = ex;
  o.y = ex + v.x;
  o.z = ex + v.x + v.y;
  o.w = ex + v.x + v.y + v.z;
  if (i + 3 < n) {
    *(int4*)(offs + i) = o;
  } else {
    if (i < n) offs[i] = o.x;
    if (i + 1 < n) offs[i + 1] = o.y;
    if (i + 2 < n) offs[i + 2] = o.z;
    if (i + 3 < n) offs[i + 3] = o.w;
  }
}

__global__ void scatter4_kernel(
    const int* s0, const int* d0, int n0, const int* f0, int* u0, int* e0,
    const int* s1, const int* d1, int n1, const int* f1, int* u1, int* e1,
    const int* s2, const int* d2, int n2, const int* f2, int* u2, int* e2,
    const int* s3, const int* d3, int n3, const int* f3, int* u3, int* e3) {
  int a = blockIdx.y;
  const int* src = a == 0 ? s0 : a == 1 ? s1 : a == 2 ? s2 : s3;
  const int* dst = a == 0 ? d0 : a == 1 ? d1 : a == 2 ? d2 : d3;
  int n = a == 0 ? n0 : a == 1 ? n1 : a == 2 ? n2 : n3;
  const int* offs = a == 0 ? f0 : a == 1 ? f1 : a == 2 ? f2 : f3;
  int* cur = a == 0 ? u0 : a == 1 ? u1 : a == 2 ? u2 : u3;
  int* elist = a == 0 ? e0 : a == 1 ? e1 : a == 2 ? e2 : e3;
  int i = blockIdx.x * blockDim.x + threadIdx.x;
  if (i < n) {
    int d = dst[i];
    int p = offs[d] + atomicAdd(&cur[d], 1);
    elist[p] = src[i];
  }
}

// ---------------- aggregation: one wave per dst node, two etypes fused ------
// Wave split into two 32-lane halves; each half handles one edge with a
// uint4 (16B) gather: 32 lanes x 16B = one full 512B row. Lane l32 covers
// channels [l32*8, l32*8+8). Main loop unrolled to keep 4 gathers in flight.
__device__ __forceinline__ void add8(float* acc, uint4 p) {
  acc[0] += bfbits2f(p.x << 16);
  acc[1] += bfbits2f(p.x & 0xffff0000u);
  acc[2] += bfbits2f(p.y << 16);
  acc[3] += bfbits2f(p.y & 0xffff0000u);
  acc[4] += bfbits2f(p.z << 16);
  acc[5] += bfbits2f(p.z & 0xffff0000u);
  acc[6] += bfbits2f(p.w << 16);
  acc[7] += bfbits2f(p.w & 0xffff0000u);
}

__global__ __launch_bounds__(256) void aggregate_kernel(
    const unsigned short* __restrict__ WhA, const int* __restrict__ offsA,
    const int* __restrict__ elistA, const unsigned short* __restrict__ WhB,
    const int* __restrict__ offsB, const int* __restrict__ elistB,
    unsigned short* __restrict__ hout, int n) {
  int wave = (blockIdx.x * 256 + threadIdx.x) >> 6;
  int lane = threadIdx.x & 63;
  if (wave >= n) return;
  int half = lane >> 5;
  int l32 = lane & 31;
  size_t coff = (size_t)l32 * 8;  // channel offset in shorts

  float accA[8] = {0, 0, 0, 0, 0, 0, 0, 0};
  float accB[8] = {0, 0, 0, 0, 0, 0, 0, 0};
  float scA, scB;

  {
    int e0 = offsA[wave], e1 = offsA[wave + 1];
    scA = 0.5f / fmaxf((float)(e1 - e0), 1.0f);
    int e = e0;
    for (; e + 8 <= e1; e += 8) {
      int s0 = elistA[e + half];
      int s1 = elistA[e + 2 + half];
      int s2 = elistA[e + 4 + half];
      int s3 = elistA[e + 6 + half];
      uint4 p0 = *(const uint4*)(WhA + (size_t)s0 * D + coff);
      uint4 p1 = *(const uint4*)(WhA + (size_t)s1 * D + coff);
      uint4 p2 = *(const uint4*)(WhA + (size_t)s2 * D + coff);
      uint4 p3 = *(const uint4*)(WhA + (size_t)s3 * D + coff);
      add8(accA, p0); add8(accA, p1); add8(accA, p2); add8(accA, p3);
    }
    for (; e + 2 <= e1; e += 2) {
      int s0 = elistA[e + half];
      uint4 p0 = *(const uint4*)(WhA + (size_t)s0 * D + coff);
      add8(accA, p0);
    }
    if (e < e1 && half == 0) {
      int s0 = elistA[e];
      uint4 p0 = *(const uint4*)(WhA + (size_t)s0 * D + coff);
      add8(accA, p0);
    }
  }
  {
    int e0 = offsB[wave], e1 = offsB[wave + 1];
    scB = 0.5f / fmaxf((float)(e1 - e0), 1.0f);
    int e = e0;
    for (; e + 8 <= e1; e += 8) {
      int s0 = elistB[e + half];
      int s1 = elistB[e + 2 + half];
      int s2 = elistB[e + 4 + half];
      int s3 = elistB[e + 6 + half];
      uint4 p0 = *(const uint4*)(WhB + (size_t)s0 * D + coff);
      uint4 p1 = *(const uint4*)(WhB + (size_t)s1 * D + coff);
      uint4 p2 = *(const uint4*)(WhB + (size_t)s2 * D + coff);
      uint4 p3 = *(const uint4*)(WhB + (size_t)s3 * D + coff);
      add8(accB, p0); add8(accB, p1); add8(accB, p2); add8(accB, p3);
    }
    for (; e + 2 <= e1; e += 2) {
      int s0 = elistB[e + half];
      uint4 p0 = *(const uint4*)(WhB + (size_t)s0 * D + coff);
      add8(accB, p0);
    }
    if (e < e1 && half == 0) {
      int s0 = elistB[e];
      uint4 p0 = *(const uint4*)(WhB + (size_t)s0 * D + coff);
      add8(accB, p0);
    }
  }

  float h[8];
#pragma unroll
  for (int j = 0; j < 8; j++) {
    h[j] = accA[j] * scA + accB[j] * scB;
    h[j] += __shfl_down(h[j], 32);
  }
  if (half == 0) {
    uint4 o;
    o.x = (unsigned)f2bf(h[0]) | ((unsigned)f2bf(h[1]) << 16);
    o.y = (unsigned)f2bf(h[2]) | ((unsigned)f2bf(h[3]) << 16);
    o.z = (unsigned)f2bf(h[4]) | ((unsigned)f2bf(h[5]) << 16);
    o.w = (unsigned)f2bf(h[6]) | ((unsigned)f2bf(h[7]) << 16);
    *(uint4*)(hout + (size_t)wave * D + coff) = o;
  }
}

// ---------------- launch ----------------
extern "C" void kernel_launch(void* const* d_in, const int* in_sizes, int n_in,
                              void* d_out, int out_size, void* d_ws,
                              size_t ws_size, hipStream_t stream) {
  const float* feat_table = (const float*)d_in[0];
  const float* feat_column = (const float*)d_in[1];
  const float* Wsrc[5] = {(const float*)d_in[2], (const float*)d_in[4],
                          (const float*)d_in[6], (const float*)d_in[8],
                          (const float*)d_in[10]};
  const float* b_t2c = (const float*)d_in[3];
  const float* b_c2t = (const float*)d_in[5];
  const float* b_c2c = (const float*)d_in[7];
  const float* b_t2t = (const float*)d_in[9];
  const float* b_h = (const float*)d_in[11];
  const int* src_t2c = (const int*)d_in[12];
  const int* dst_t2c = (const int*)d_in[13];
  const int* src_c2t = (const int*)d_in[14];
  const int* dst_c2t = (const int*)d_in[15];
  const int* src_c2c = (const int*)d_in[16];
  const int* dst_c2c = (const int*)d_in[17];
  const int* src_t2t = (const int*)d_in[18];
  const int* dst_t2t = (const int*)d_in[19];

  const int NT = in_sizes[0] / D;
  const int NC = in_sizes[1] / D;
  const int E_t2c = in_sizes[12], E_c2t = in_sizes[14];
  const int E_c2c = in_sizes[16], E_t2t = in_sizes[18];

  char* ws = (char*)d_ws;
  size_t cur = 0;
  auto alloc = [&](size_t bytes) -> void* {
    void* p = ws + cur;
    cur += (bytes + 255) & ~(size_t)255;
    return p;
  };
  unsigned short* Wb[5];
  for (int i = 0; i < 5; i++) Wb[i] = (unsigned short*)alloc((size_t)D * D * 2);
  unsigned short* ftb = (unsigned short*)alloc((size_t)NT * D * 2);
  unsigned short* fcb = (unsigned short*)alloc((size_t)NC * D * 2);
  unsigned short* Wh_t2c = (unsigned short*)alloc((size_t)NT * D * 2);
  unsigned short* Wh_c2t = (unsigned short*)alloc((size_t)NC * D * 2);
  unsigned short* Wh_c2c = (unsigned short*)alloc((size_t)NC * D * 2);
  unsigned short* Wh_t2t = (unsigned short*)alloc((size_t)NT * D * 2);
  unsigned short* h_tab = (unsigned short*)alloc((size_t)NT * D * 2);
  unsigned short* h_col = (unsigned short*)alloc((size_t)NC * D * 2);
  int* ints = (int*)alloc(sizeof(int) * 2 * (2 * (size_t)NT + 2 * (size_t)NC));
  int* cnt_c2t = ints;
  int* cnt_t2t = cnt_c2t + NT;
  int* cnt_t2c = cnt_t2t + NT;
  int* cnt_c2c = cnt_t2c + NC;
  int* cur_c2t = cnt_c2c + NC;
  int* cur_t2t = cur_c2t + NT;
  int* cur_t2c = cur_t2t + NT;
  int* cur_c2c = cur_t2c + NC;
  int* off_c2t = (int*)alloc(sizeof(int) * (NT + 1));
  int* off_t2t = (int*)alloc(sizeof(int) * (NT + 1));
  int* off_t2c = (int*)alloc(sizeof(int) * (NC + 1));
  int* off_c2c = (int*)alloc(sizeof(int) * (NC + 1));
  int* el_c2t = (int*)alloc(sizeof(int) * E_c2t);
  int* el_t2t = (int*)alloc(sizeof(int) * E_t2t);
  int* el_t2c = (int*)alloc(sizeof(int) * E_t2c);
  int* el_c2c = (int*)alloc(sizeof(int) * E_c2c);
  int* bsum = (int*)alloc(sizeof(int) * 4 * 128);

  hipMemsetAsync(ints, 0, sizeof(int) * 2 * (2 * (size_t)NT + 2 * (size_t)NC),
                 stream);

  // casts
  {
    dim3 g((D * D / 4 + 255) / 256, 5);
    cast5_kernel<<<g, 256, 0, stream>>>(Wsrc[0], Wsrc[1], Wsrc[2], Wsrc[3],
                                        Wsrc[4], Wb[0], Wb[1], Wb[2], Wb[3],
                                        Wb[4]);
  }
  cast_kernel<<<((NT * D / 4) + 255) / 256, 256, 0, stream>>>(feat_table, ftb,
                                                              NT * D / 4);
  cast_kernel<<<((NC * D / 4) + 255) / 256, 256, 0, stream>>>(feat_column, fcb,
                                                              NC * D / 4);

  // Wh = lrelu(feat @ W^T + b), bf16 out
  {
    dim3 g(2, (NT + 127) / 128);
    gemm_bt<0><<<g, 256, 0, stream>>>(ftb, Wb[0], b_t2c, nullptr, Wh_t2c,
                                      nullptr, NT);
    gemm_bt<0><<<g, 256, 0, stream>>>(ftb, Wb[3], b_t2t, nullptr, Wh_t2t,
                                      nullptr, NT);
  }
  {
    dim3 g(2, (NC + 127) / 128);
    gemm_bt<0><<<g, 256, 0, stream>>>(fcb, Wb[1], b_c2t, nullptr, Wh_c2t,
                                      nullptr, NC);
    gemm_bt<0><<<g, 256, 0, stream>>>(fcb, Wb[2], b_c2c, nullptr, Wh_c2c,
                                      nullptr, NC);
  }

  // CSR build: hist -> 3-phase scan -> scatter
  int Emax = max(max(E_c2t, E_t2t), max(E_t2c, E_c2c));
  {
    dim3 g((Emax + 255) / 256, 4);
    hist4_kernel<<<g, 256, 0, stream>>>(dst_c2t, E_c2t, cnt_c2t, dst_t2t,
                                        E_t2t, cnt_t2t, dst_t2c, E_t2c,
                                        cnt_t2c, dst_c2c, E_c2c, cnt_c2c);
  }
  int nmax = max(NT, NC);
  {
    dim3 g((nmax + 1023) / 1024, 4);
    scan_p1<<<g, 256, 0, stream>>>(cnt_c2t, NT, cnt_t2t, NT, cnt_t2c, NC,
                                   cnt_c2c, NC, bsum);
    scan_p2<<<4, 128, 0, stream>>>(bsum, off_c2t, NT, off_t2t, NT, off_t2c, NC,
                                   off_c2c, NC);
    scan_p3<<<g, 256, 0, stream>>>(cnt_c2t, off_c2t, NT, cnt_t2t, off_t2t, NT,
                                   cnt_t2c, off_t2c, NC, cnt_c2c, off_c2c, NC,
                                   bsum);
  }
  {
    dim3 g((Emax + 255) / 256, 4);
    scatter4_kernel<<<g, 256, 0, stream>>>(
        src_c2t, dst_c2t, E_c2t, off_c2t, cur_c2t, el_c2t, src_t2t, dst_t2t,
        E_t2t, off_t2t, cur_t2t, el_t2t, src_t2c, dst_t2c, E_t2c, off_t2c,
        cur_t2c, el_t2c, src_c2c, dst_c2c, E_c2c, off_c2c, cur_c2c, el_c2c);
  }

  // h = 0.5*(meanA + meanB), bf16 out
  aggregate_kernel<<<(NT + 3) / 4, 256, 0, stream>>>(
      Wh_c2t, off_c2t, el_c2t, Wh_t2t, off_t2t, el_t2t, h_tab, NT);
  aggregate_kernel<<<(NC + 3) / 4, 256, 0, stream>>>(
      Wh_t2c, off_t2c, el_t2c, Wh_c2c, off_c2c, el_c2c, h_col, NC);

  // out = lrelu(h @ W_h^T + b_h) + feat, fp32 out
  float* out_tab = (float*)d_out;
  float* out_col = out_tab + (size_t)NT * D;
  {
    dim3 g(2, (NT + 127) / 128);
    gemm_bt<1><<<g, 256, 0, stream>>>(h_tab, Wb[4], b_h, feat_table, nullptr,
                                      out_tab, NT);
  }
  {
    dim3 g(2, (NC + 127) / 128);
    gemm_bt<1><<<g, 256, 0, stream>>>(h_col, Wb[4], b_h, feat_column, nullptr,
                                      out_col, NC);
  }
}